// Round 3
// baseline (553.844 us; speedup 1.0000x reference)
//
#include <hip/hip_runtime.h>
#include <cstdint>
#include <cstddef>

#define GN 16384          // nodes
#define GF 64             // features
#define NW (GN / 32)      // 512 dwords per packed bit-row

typedef __bf16 bf16x8 __attribute__((ext_vector_type(8)));
typedef float f32x4 __attribute__((ext_vector_type(4)));
typedef unsigned int u32x4 __attribute__((ext_vector_type(4)));

// ROUND-1 decode (kept byte-identical for clean A/B attribution).
__device__ __forceinline__ bf16x8 decode8(unsigned int t) {
  u32x4 r;
#pragma unroll
  for (int d = 0; d < 4; ++d) {
    unsigned int u = t >> (2 * d);
    r[d] = ((u & 1u) * 0x3F80u) | ((u & 2u) * 0x1FC00000u);
  }
  return __builtin_bit_cast(bf16x8, r);
}

__device__ __forceinline__ unsigned short f2bf(float v) {  // RNE f32->bf16
  unsigned int u = __builtin_bit_cast(unsigned int, v);
  u += 0x7fffu + ((u >> 16) & 1u);
  return (unsigned short)(u >> 16);
}

__device__ __forceinline__ float bf2f(unsigned short s) {
  return __builtin_bit_cast(float, (unsigned int)s << 16);
}

// ---------------------------------------------------------------------------
// K1 (UNCHANGED): read adj (1 GiB): column sums (deg) + transposed bitmask.
// THIS ROUND IT RUNS TWICE (attribution): pass 1 -> deg_dummy, pass 2 -> deg.
// ---------------------------------------------------------------------------
__global__ __launch_bounds__(256) void k_pack(const float* __restrict__ adj,
                                              float* __restrict__ deg,
                                              unsigned int* __restrict__ packed) {
  const int cb = blockIdx.x >> 5;
  const int jb = blockIdx.x & 31;
  const int col0 = cb * 1024 + threadIdx.x * 4;
  const int j0 = jb * 512;
  int cnt0 = 0, cnt1 = 0, cnt2 = 0, cnt3 = 0;

  for (int seg = 0; seg < 4; ++seg) {
    u32x4 v0, v1, v2, v3;
#pragma unroll
    for (int q = 0; q < 4; ++q) {
      unsigned int w0 = 0, w1 = 0, w2 = 0, w3 = 0;
      const float* base = adj + (size_t)(j0 + seg * 128 + q * 32) * GN + col0;
#pragma unroll 8
      for (int b = 0; b < 32; ++b) {
        f32x4 a = *(const f32x4*)(base + (size_t)b * GN);
        unsigned int m = 1u << b;
        if (a.x != 0.f) w0 |= m;
        if (a.y != 0.f) w1 |= m;
        if (a.z != 0.f) w2 |= m;
        if (a.w != 0.f) w3 |= m;
      }
      v0[q] = w0; v1[q] = w1; v2[q] = w2; v3[q] = w3;
      cnt0 += __popc(w0); cnt1 += __popc(w1); cnt2 += __popc(w2); cnt3 += __popc(w3);
    }
    const size_t wbase = (size_t)jb * 16 + seg * 4;
    *(u32x4*)(packed + (size_t)(col0 + 0) * NW + wbase) = v0;
    *(u32x4*)(packed + (size_t)(col0 + 1) * NW + wbase) = v1;
    *(u32x4*)(packed + (size_t)(col0 + 2) * NW + wbase) = v2;
    *(u32x4*)(packed + (size_t)(col0 + 3) * NW + wbase) = v3;
  }
  atomicAdd(&deg[col0 + 0], (float)cnt0);
  atomicAdd(&deg[col0 + 1], (float)cnt1);
  atomicAdd(&deg[col0 + 2], (float)cnt2);
  atomicAdd(&deg[col0 + 3], (float)cnt3);
}

// ---------------------------------------------------------------------------
// K2 (UNCHANGED): z = dinv * (x@W); emit z row-major bf16, z^T bf16, dinv.
// ---------------------------------------------------------------------------
__global__ __launch_bounds__(256) void k_z(const float* __restrict__ x,
                                           const float* __restrict__ W,
                                           const float* __restrict__ deg,
                                           float* __restrict__ dinv,
                                           unsigned short* __restrict__ z_rm,
                                           unsigned short* __restrict__ zT) {
  __shared__ float Wl[64][64];
  __shared__ float xl[64][64];
  const int tid = threadIdx.x;
  const int f = tid & 63;
  const int w = tid >> 6;
  const int rowB = blockIdx.x * 64;

  for (int idx = tid; idx < 4096; idx += 256) {
    Wl[idx >> 6][idx & 63] = W[idx];
    xl[idx >> 6][idx & 63] = x[(size_t)rowB * 64 + idx];
  }
  __syncthreads();

  float acc[16];
#pragma unroll
  for (int r = 0; r < 16; ++r) acc[r] = 0.f;
  for (int k = 0; k < 64; ++k) {
    float wk = Wl[k][f];
#pragma unroll
    for (int r = 0; r < 16; ++r) acc[r] = fmaf(xl[w * 16 + r][k], wk, acc[r]);
  }

  const int row0 = rowB + w * 16;
  if (f < 16) {
    int row = row0 + f;
    dinv[row] = 1.0f / sqrtf(deg[row] + 1.0f);
  }

  unsigned short zs[16];
#pragma unroll
  for (int r = 0; r < 16; ++r) {
    int row = row0 + r;
    float di = 1.0f / sqrtf(deg[row] + 1.0f);
    unsigned short zb = f2bf(di * acc[r]);
    zs[r] = zb;
    z_rm[(size_t)row * GF + f] = zb;
  }
  unsigned int p[8];
#pragma unroll
  for (int i = 0; i < 8; ++i)
    p[i] = (unsigned int)zs[2 * i] | ((unsigned int)zs[2 * i + 1] << 16);
  u32x4 lo = {p[0], p[1], p[2], p[3]};
  u32x4 hi = {p[4], p[5], p[6], p[7]};
  *(u32x4*)(zT + (size_t)f * GN + row0) = lo;
  *(u32x4*)(zT + (size_t)f * GN + row0 + 8) = hi;
}

// ---------------------------------------------------------------------------
// K3: EXACT ROUND-1 VERSION (v1): 256 threads, 4 waves = 4 K-quarters,
// acc[4][4], original decode. Reverted for clean attribution.
// ---------------------------------------------------------------------------
__global__ __launch_bounds__(256) void k_spmm(const unsigned int* __restrict__ packed,
                                              const unsigned short* __restrict__ zT,
                                              const unsigned short* __restrict__ z_rm,
                                              const float* __restrict__ dinv,
                                              const float* __restrict__ bias,
                                              float* __restrict__ out) {
  __shared__ float red[4][64][64];  // 64 KB split-K partials
  const int i0 = blockIdx.x * 64;
  const int tid = threadIdx.x;
  const int wave = tid >> 6, lane = tid & 63;
  const int lrow = lane & 15, kb = lane >> 4;

  f32x4 acc[4][4];
#pragma unroll
  for (int mr = 0; mr < 4; ++mr)
#pragma unroll
    for (int nr = 0; nr < 4; ++nr) acc[mr][nr] = (f32x4){0.f, 0.f, 0.f, 0.f};

  const unsigned int* pr0 = packed + (size_t)(i0 + 0 * 16 + lrow) * NW + wave * 128;
  const unsigned int* pr1 = packed + (size_t)(i0 + 1 * 16 + lrow) * NW + wave * 128;
  const unsigned int* pr2 = packed + (size_t)(i0 + 2 * 16 + lrow) * NW + wave * 128;
  const unsigned int* pr3 = packed + (size_t)(i0 + 3 * 16 + lrow) * NW + wave * 128;
  const unsigned short* zb0 = zT + (size_t)(0 * 16 + lrow) * GN + wave * 4096 + kb * 8;
  const unsigned short* zb1 = zT + (size_t)(1 * 16 + lrow) * GN + wave * 4096 + kb * 8;
  const unsigned short* zb2 = zT + (size_t)(2 * 16 + lrow) * GN + wave * 4096 + kb * 8;
  const unsigned short* zb3 = zT + (size_t)(3 * 16 + lrow) * GN + wave * 4096 + kb * 8;
  const int sh = kb * 8;

  for (int it = 0; it < 32; ++it) {  // 128 k per iter
    u32x4 bits0 = *(const u32x4*)pr0;
    u32x4 bits1 = *(const u32x4*)pr1;
    u32x4 bits2 = *(const u32x4*)pr2;
    u32x4 bits3 = *(const u32x4*)pr3;
#pragma unroll
    for (int s = 0; s < 4; ++s) {    // 4 MFMA k-steps of 32
      bf16x8 bf[4];
      bf[0] = *(const bf16x8*)(zb0 + s * 32);
      bf[1] = *(const bf16x8*)(zb1 + s * 32);
      bf[2] = *(const bf16x8*)(zb2 + s * 32);
      bf[3] = *(const bf16x8*)(zb3 + s * 32);

      bf16x8 a0 = decode8((bits0[s] >> sh) & 0xffu);
#pragma unroll
      for (int nr = 0; nr < 4; ++nr)
        acc[0][nr] = __builtin_amdgcn_mfma_f32_16x16x32_bf16(a0, bf[nr], acc[0][nr], 0, 0, 0);
      bf16x8 a1 = decode8((bits1[s] >> sh) & 0xffu);
#pragma unroll
      for (int nr = 0; nr < 4; ++nr)
        acc[1][nr] = __builtin_amdgcn_mfma_f32_16x16x32_bf16(a1, bf[nr], acc[1][nr], 0, 0, 0);
      bf16x8 a2 = decode8((bits2[s] >> sh) & 0xffu);
#pragma unroll
      for (int nr = 0; nr < 4; ++nr)
        acc[2][nr] = __builtin_amdgcn_mfma_f32_16x16x32_bf16(a2, bf[nr], acc[2][nr], 0, 0, 0);
      bf16x8 a3 = decode8((bits3[s] >> sh) & 0xffu);
#pragma unroll
      for (int nr = 0; nr < 4; ++nr)
        acc[3][nr] = __builtin_amdgcn_mfma_f32_16x16x32_bf16(a3, bf[nr], acc[3][nr], 0, 0, 0);
    }
    pr0 += 4; pr1 += 4; pr2 += 4; pr3 += 4;
    zb0 += 128; zb1 += 128; zb2 += 128; zb3 += 128;
  }

#pragma unroll
  for (int mr = 0; mr < 4; ++mr)
#pragma unroll
    for (int nr = 0; nr < 4; ++nr)
#pragma unroll
      for (int r = 0; r < 4; ++r)
        red[wave][mr * 16 + kb * 4 + r][nr * 16 + lrow] = acc[mr][nr][r];
  __syncthreads();

  const int c = tid & 63;
  const int r0 = tid >> 6;
  const float bc = bias[c];
#pragma unroll
  for (int rr = 0; rr < 16; ++rr) {
    int r = r0 * 16 + rr;
    int i = i0 + r;
    float s = red[0][r][c] + red[1][r][c] + red[2][r][c] + red[3][r][c];
    float o = dinv[i] * (s + bf2f(z_rm[(size_t)i * GF + c])) + bc;
    out[(size_t)i * GF + c] = fmaxf(o, 0.f);
  }
}

// ---------------------------------------------------------------------------
// ATTRIBUTION ROUND: k_pack runs TWICE (pass1 -> deg_dummy, pass2 -> deg).
// T(k_pack) = R3_total - R1_total(325us). Everything else identical to R1.
// ---------------------------------------------------------------------------
extern "C" void kernel_launch(void* const* d_in, const int* in_sizes, int n_in,
                              void* d_out, int out_size, void* d_ws, size_t ws_size,
                              hipStream_t stream) {
  const float* x = (const float*)d_in[0];
  const float* adj = (const float*)d_in[1];
  const float* W = (const float*)d_in[2];
  const float* bias = (const float*)d_in[3];
  float* out = (float*)d_out;

  char* ws = (char*)d_ws;
  float* deg = (float*)ws;                                        // 64 KB
  float* deg_dummy = (float*)(ws + 65536);                        // 64 KB
  float* dinv = (float*)(ws + 131072);                            // 64 KB
  unsigned short* z_rm = (unsigned short*)(ws + 196608);          // 2 MB
  unsigned short* zT = (unsigned short*)(ws + 196608 + 2097152);  // 2 MB
  unsigned int* packed = (unsigned int*)(ws + 196608 + 4194304);  // 32 MB
  if (ws_size < 37945344u) return;

  hipMemsetAsync(deg, 0, 2 * GN * sizeof(float), stream);  // deg + deg_dummy
  k_pack<<<dim3(512), dim3(256), 0, stream>>>(adj, deg_dummy, packed);  // timing probe
  k_pack<<<dim3(512), dim3(256), 0, stream>>>(adj, deg, packed);
  k_z<<<dim3(GN / 64), dim3(256), 0, stream>>>(x, W, deg, dinv, z_rm, zT);
  k_spmm<<<dim3(GN / 64), dim3(256), 0, stream>>>(packed, zT, z_rm, dinv, bias, out);
}

// Round 4
// 315.321 us; speedup vs baseline: 1.7564x; 1.7564x over previous
//
#include <hip/hip_runtime.h>
#include <cstdint>
#include <cstddef>

#define GN 16384          // nodes
#define GF 64             // features
#define NW (GN / 32)      // 512 dwords per packed bit-row

typedef __bf16 bf16x8 __attribute__((ext_vector_type(8)));
typedef float f32x4 __attribute__((ext_vector_type(4)));
typedef unsigned int u32x4 __attribute__((ext_vector_type(4)));

// ROUND-1 decode (unchanged).
__device__ __forceinline__ bf16x8 decode8(unsigned int t) {
  u32x4 r;
#pragma unroll
  for (int d = 0; d < 4; ++d) {
    unsigned int u = t >> (2 * d);
    r[d] = ((u & 1u) * 0x3F80u) | ((u & 2u) * 0x1FC00000u);
  }
  return __builtin_bit_cast(bf16x8, r);
}

__device__ __forceinline__ unsigned short f2bf(float v) {  // RNE f32->bf16
  unsigned int u = __builtin_bit_cast(unsigned int, v);
  u += 0x7fffu + ((u >> 16) & 1u);
  return (unsigned short)(u >> 16);
}

__device__ __forceinline__ float bf2f(unsigned short s) {
  return __builtin_bit_cast(float, (unsigned int)s << 16);
}

// ---------------------------------------------------------------------------
// K1 (byte-identical to R1): adj (1 GiB) -> column sums + transposed bitmask.
// ---------------------------------------------------------------------------
__global__ __launch_bounds__(256) void k_pack(const float* __restrict__ adj,
                                              float* __restrict__ deg,
                                              unsigned int* __restrict__ packed) {
  const int cb = blockIdx.x >> 5;
  const int jb = blockIdx.x & 31;
  const int col0 = cb * 1024 + threadIdx.x * 4;
  const int j0 = jb * 512;
  int cnt0 = 0, cnt1 = 0, cnt2 = 0, cnt3 = 0;

  for (int seg = 0; seg < 4; ++seg) {
    u32x4 v0, v1, v2, v3;
#pragma unroll
    for (int q = 0; q < 4; ++q) {
      unsigned int w0 = 0, w1 = 0, w2 = 0, w3 = 0;
      const float* base = adj + (size_t)(j0 + seg * 128 + q * 32) * GN + col0;
#pragma unroll 8
      for (int b = 0; b < 32; ++b) {
        f32x4 a = *(const f32x4*)(base + (size_t)b * GN);
        unsigned int m = 1u << b;
        if (a.x != 0.f) w0 |= m;
        if (a.y != 0.f) w1 |= m;
        if (a.z != 0.f) w2 |= m;
        if (a.w != 0.f) w3 |= m;
      }
      v0[q] = w0; v1[q] = w1; v2[q] = w2; v3[q] = w3;
      cnt0 += __popc(w0); cnt1 += __popc(w1); cnt2 += __popc(w2); cnt3 += __popc(w3);
    }
    const size_t wbase = (size_t)jb * 16 + seg * 4;
    *(u32x4*)(packed + (size_t)(col0 + 0) * NW + wbase) = v0;
    *(u32x4*)(packed + (size_t)(col0 + 1) * NW + wbase) = v1;
    *(u32x4*)(packed + (size_t)(col0 + 2) * NW + wbase) = v2;
    *(u32x4*)(packed + (size_t)(col0 + 3) * NW + wbase) = v3;
  }
  atomicAdd(&deg[col0 + 0], (float)cnt0);
  atomicAdd(&deg[col0 + 1], (float)cnt1);
  atomicAdd(&deg[col0 + 2], (float)cnt2);
  atomicAdd(&deg[col0 + 3], (float)cnt3);
}

// ---------------------------------------------------------------------------
// K2: z = dinv * (x@W); emit z row-major bf16 + CHUNK-TILED z2.
// Z2[jc][f][jj]: node-chunk jc = j>>5, feature f, jj = j&31. Each 4 KB chunk
// holds all 64 features x 32 nodes contiguously -> spmm B-loads coalesce.
// ---------------------------------------------------------------------------
__global__ __launch_bounds__(256) void k_z(const float* __restrict__ x,
                                           const float* __restrict__ W,
                                           const float* __restrict__ deg,
                                           float* __restrict__ dinv,
                                           unsigned short* __restrict__ z_rm,
                                           unsigned short* __restrict__ z2) {
  __shared__ float Wl[64][64];
  __shared__ float xl[64][64];
  const int tid = threadIdx.x;
  const int f = tid & 63;
  const int w = tid >> 6;
  const int rowB = blockIdx.x * 64;

  for (int idx = tid; idx < 4096; idx += 256) {
    Wl[idx >> 6][idx & 63] = W[idx];
    xl[idx >> 6][idx & 63] = x[(size_t)rowB * 64 + idx];
  }
  __syncthreads();

  float acc[16];
#pragma unroll
  for (int r = 0; r < 16; ++r) acc[r] = 0.f;
  for (int k = 0; k < 64; ++k) {
    float wk = Wl[k][f];
#pragma unroll
    for (int r = 0; r < 16; ++r) acc[r] = fmaf(xl[w * 16 + r][k], wk, acc[r]);
  }

  const int row0 = rowB + w * 16;
  if (f < 16) {
    int row = row0 + f;
    dinv[row] = 1.0f / sqrtf(deg[row] + 1.0f);
  }

  unsigned short zs[16];
#pragma unroll
  for (int r = 0; r < 16; ++r) {
    int row = row0 + r;
    float di = 1.0f / sqrtf(deg[row] + 1.0f);
    unsigned short zb = f2bf(di * acc[r]);
    zs[r] = zb;
    z_rm[(size_t)row * GF + f] = zb;
  }
  unsigned int p[8];
#pragma unroll
  for (int i = 0; i < 8; ++i)
    p[i] = (unsigned int)zs[2 * i] | ((unsigned int)zs[2 * i + 1] << 16);
  // Z2 byte addr for (f, j=row0+r): jc*4096 + f*64 + (j&31)*2.
  // This thread: jc = rowB/32 + (w>>1), jj runs (w&1)*16 .. +15 -> 32 B.
  char* dst = (char*)z2 + (size_t)((rowB >> 5) + (w >> 1)) * 4096 + f * 64 + (w & 1) * 32;
  u32x4 lo = {p[0], p[1], p[2], p[3]};
  u32x4 hi = {p[4], p[5], p[6], p[7]};
  *(u32x4*)dst = lo;
  *(u32x4*)(dst + 16) = hi;
}

// ---------------------------------------------------------------------------
// K3: structure identical to R1 (256 thr, 4 waves = 4 K-quarters, acc[4][4]);
// ONLY the z addressing changed to the chunk-tiled Z2 layout. Each B-fragment
// load is now one contiguous 1 KB wave-read; each s-step streams a 4 KB chunk.
// ---------------------------------------------------------------------------
__global__ __launch_bounds__(256) void k_spmm(const unsigned int* __restrict__ packed,
                                              const unsigned short* __restrict__ z2,
                                              const unsigned short* __restrict__ z_rm,
                                              const float* __restrict__ dinv,
                                              const float* __restrict__ bias,
                                              float* __restrict__ out) {
  __shared__ float red[4][64][64];  // 64 KB split-K partials
  const int i0 = blockIdx.x * 64;
  const int tid = threadIdx.x;
  const int wave = tid >> 6, lane = tid & 63;
  const int lrow = lane & 15, kb = lane >> 4;

  f32x4 acc[4][4];
#pragma unroll
  for (int mr = 0; mr < 4; ++mr)
#pragma unroll
    for (int nr = 0; nr < 4; ++nr) acc[mr][nr] = (f32x4){0.f, 0.f, 0.f, 0.f};

  const unsigned int* pr0 = packed + (size_t)(i0 + 0 * 16 + lrow) * NW + wave * 128;
  const unsigned int* pr1 = packed + (size_t)(i0 + 1 * 16 + lrow) * NW + wave * 128;
  const unsigned int* pr2 = packed + (size_t)(i0 + 2 * 16 + lrow) * NW + wave * 128;
  const unsigned int* pr3 = packed + (size_t)(i0 + 3 * 16 + lrow) * NW + wave * 128;
  // Z2: chunk = kq*128 + it*4 + s; lane byte offset lrow*64 + kb*16.
  const char* zbase = (const char*)z2 + (size_t)(wave * 128) * 4096 + lrow * 64 + kb * 16;
  const int sh = kb * 8;

  for (int it = 0; it < 32; ++it) {  // 128 k per iter = 4 chunks
    u32x4 bits0 = *(const u32x4*)pr0;
    u32x4 bits1 = *(const u32x4*)pr1;
    u32x4 bits2 = *(const u32x4*)pr2;
    u32x4 bits3 = *(const u32x4*)pr3;
#pragma unroll
    for (int s = 0; s < 4; ++s) {    // 4 MFMA k-steps of 32
      bf16x8 bf[4];
      bf[0] = *(const bf16x8*)(zbase + s * 4096 + 0 * 1024);
      bf[1] = *(const bf16x8*)(zbase + s * 4096 + 1 * 1024);
      bf[2] = *(const bf16x8*)(zbase + s * 4096 + 2 * 1024);
      bf[3] = *(const bf16x8*)(zbase + s * 4096 + 3 * 1024);

      bf16x8 a0 = decode8((bits0[s] >> sh) & 0xffu);
#pragma unroll
      for (int nr = 0; nr < 4; ++nr)
        acc[0][nr] = __builtin_amdgcn_mfma_f32_16x16x32_bf16(a0, bf[nr], acc[0][nr], 0, 0, 0);
      bf16x8 a1 = decode8((bits1[s] >> sh) & 0xffu);
#pragma unroll
      for (int nr = 0; nr < 4; ++nr)
        acc[1][nr] = __builtin_amdgcn_mfma_f32_16x16x32_bf16(a1, bf[nr], acc[1][nr], 0, 0, 0);
      bf16x8 a2 = decode8((bits2[s] >> sh) & 0xffu);
#pragma unroll
      for (int nr = 0; nr < 4; ++nr)
        acc[2][nr] = __builtin_amdgcn_mfma_f32_16x16x32_bf16(a2, bf[nr], acc[2][nr], 0, 0, 0);
      bf16x8 a3 = decode8((bits3[s] >> sh) & 0xffu);
#pragma unroll
      for (int nr = 0; nr < 4; ++nr)
        acc[3][nr] = __builtin_amdgcn_mfma_f32_16x16x32_bf16(a3, bf[nr], acc[3][nr], 0, 0, 0);
    }
    pr0 += 4; pr1 += 4; pr2 += 4; pr3 += 4;
    zbase += 16384;  // 4 chunks
  }

#pragma unroll
  for (int mr = 0; mr < 4; ++mr)
#pragma unroll
    for (int nr = 0; nr < 4; ++nr)
#pragma unroll
      for (int r = 0; r < 4; ++r)
        red[wave][mr * 16 + kb * 4 + r][nr * 16 + lrow] = acc[mr][nr][r];
  __syncthreads();

  const int c = tid & 63;
  const int r0 = tid >> 6;
  const float bc = bias[c];
#pragma unroll
  for (int rr = 0; rr < 16; ++rr) {
    int r = r0 * 16 + rr;
    int i = i0 + r;
    float s = red[0][r][c] + red[1][r][c] + red[2][r][c] + red[3][r][c];
    float o = dinv[i] * (s + bf2f(z_rm[(size_t)i * GF + c])) + bc;
    out[(size_t)i * GF + c] = fmaxf(o, 0.f);
  }
}

// ---------------------------------------------------------------------------
extern "C" void kernel_launch(void* const* d_in, const int* in_sizes, int n_in,
                              void* d_out, int out_size, void* d_ws, size_t ws_size,
                              hipStream_t stream) {
  const float* x = (const float*)d_in[0];
  const float* adj = (const float*)d_in[1];
  const float* W = (const float*)d_in[2];
  const float* bias = (const float*)d_in[3];
  float* out = (float*)d_out;

  char* ws = (char*)d_ws;
  float* deg = (float*)ws;                                        // 64 KB
  float* dinv = (float*)(ws + 65536);                             // 64 KB
  unsigned short* z_rm = (unsigned short*)(ws + 131072);          // 2 MB
  unsigned short* z2 = (unsigned short*)(ws + 131072 + 2097152);  // 2 MB chunk-tiled
  unsigned int* packed = (unsigned int*)(ws + 131072 + 4194304);  // 32 MB
  if (ws_size < 37879808u) return;

  hipMemsetAsync(deg, 0, GN * sizeof(float), stream);
  k_pack<<<dim3(512), dim3(256), 0, stream>>>(adj, deg, packed);
  k_z<<<dim3(GN / 64), dim3(256), 0, stream>>>(x, W, deg, dinv, z_rm, z2);
  k_spmm<<<dim3(GN / 64), dim3(256), 0, stream>>>(packed, z2, z_rm, dinv, bias, out);
}

// Round 5
// 299.912 us; speedup vs baseline: 1.8467x; 1.0514x over previous
//
#include <hip/hip_runtime.h>
#include <cstdint>
#include <cstddef>

#define GN 16384          // nodes
#define GF 64             // features
#define NW (GN / 32)      // 512 dwords per packed bit-row

typedef __bf16 bf16x8 __attribute__((ext_vector_type(8)));
typedef float f32x4 __attribute__((ext_vector_type(4)));
typedef unsigned int u32x4 __attribute__((ext_vector_type(4)));

// ROUND-1 decode (unchanged).
__device__ __forceinline__ bf16x8 decode8(unsigned int t) {
  u32x4 r;
#pragma unroll
  for (int d = 0; d < 4; ++d) {
    unsigned int u = t >> (2 * d);
    r[d] = ((u & 1u) * 0x3F80u) | ((u & 2u) * 0x1FC00000u);
  }
  return __builtin_bit_cast(bf16x8, r);
}

__device__ __forceinline__ unsigned short f2bf(float v) {  // RNE f32->bf16
  unsigned int u = __builtin_bit_cast(unsigned int, v);
  u += 0x7fffu + ((u >> 16) & 1u);
  return (unsigned short)(u >> 16);
}

__device__ __forceinline__ float bf2f(unsigned short s) {
  return __builtin_bit_cast(float, (unsigned int)s << 16);
}

// ---------------------------------------------------------------------------
// K1 (byte-identical to R1/R4): adj (1 GiB) -> column sums + transposed bitmask.
// ---------------------------------------------------------------------------
__global__ __launch_bounds__(256) void k_pack(const float* __restrict__ adj,
                                              float* __restrict__ deg,
                                              unsigned int* __restrict__ packed) {
  const int cb = blockIdx.x >> 5;
  const int jb = blockIdx.x & 31;
  const int col0 = cb * 1024 + threadIdx.x * 4;
  const int j0 = jb * 512;
  int cnt0 = 0, cnt1 = 0, cnt2 = 0, cnt3 = 0;

  for (int seg = 0; seg < 4; ++seg) {
    u32x4 v0, v1, v2, v3;
#pragma unroll
    for (int q = 0; q < 4; ++q) {
      unsigned int w0 = 0, w1 = 0, w2 = 0, w3 = 0;
      const float* base = adj + (size_t)(j0 + seg * 128 + q * 32) * GN + col0;
#pragma unroll 8
      for (int b = 0; b < 32; ++b) {
        f32x4 a = *(const f32x4*)(base + (size_t)b * GN);
        unsigned int m = 1u << b;
        if (a.x != 0.f) w0 |= m;
        if (a.y != 0.f) w1 |= m;
        if (a.z != 0.f) w2 |= m;
        if (a.w != 0.f) w3 |= m;
      }
      v0[q] = w0; v1[q] = w1; v2[q] = w2; v3[q] = w3;
      cnt0 += __popc(w0); cnt1 += __popc(w1); cnt2 += __popc(w2); cnt3 += __popc(w3);
    }
    const size_t wbase = (size_t)jb * 16 + seg * 4;
    *(u32x4*)(packed + (size_t)(col0 + 0) * NW + wbase) = v0;
    *(u32x4*)(packed + (size_t)(col0 + 1) * NW + wbase) = v1;
    *(u32x4*)(packed + (size_t)(col0 + 2) * NW + wbase) = v2;
    *(u32x4*)(packed + (size_t)(col0 + 3) * NW + wbase) = v3;
  }
  atomicAdd(&deg[col0 + 0], (float)cnt0);
  atomicAdd(&deg[col0 + 1], (float)cnt1);
  atomicAdd(&deg[col0 + 2], (float)cnt2);
  atomicAdd(&deg[col0 + 3], (float)cnt3);
}

// ---------------------------------------------------------------------------
// K2 (byte-identical to R4): z = dinv*(x@W); z row-major bf16 + chunk-tiled z2.
// Z2[jc][f][jj]: 4 KB chunk = 64 features x 32 nodes contiguous.
// ---------------------------------------------------------------------------
__global__ __launch_bounds__(256) void k_z(const float* __restrict__ x,
                                           const float* __restrict__ W,
                                           const float* __restrict__ deg,
                                           float* __restrict__ dinv,
                                           unsigned short* __restrict__ z_rm,
                                           unsigned short* __restrict__ z2) {
  __shared__ float Wl[64][64];
  __shared__ float xl[64][64];
  const int tid = threadIdx.x;
  const int f = tid & 63;
  const int w = tid >> 6;
  const int rowB = blockIdx.x * 64;

  for (int idx = tid; idx < 4096; idx += 256) {
    Wl[idx >> 6][idx & 63] = W[idx];
    xl[idx >> 6][idx & 63] = x[(size_t)rowB * 64 + idx];
  }
  __syncthreads();

  float acc[16];
#pragma unroll
  for (int r = 0; r < 16; ++r) acc[r] = 0.f;
  for (int k = 0; k < 64; ++k) {
    float wk = Wl[k][f];
#pragma unroll
    for (int r = 0; r < 16; ++r) acc[r] = fmaf(xl[w * 16 + r][k], wk, acc[r]);
  }

  const int row0 = rowB + w * 16;
  if (f < 16) {
    int row = row0 + f;
    dinv[row] = 1.0f / sqrtf(deg[row] + 1.0f);
  }

  unsigned short zs[16];
#pragma unroll
  for (int r = 0; r < 16; ++r) {
    int row = row0 + r;
    float di = 1.0f / sqrtf(deg[row] + 1.0f);
    unsigned short zb = f2bf(di * acc[r]);
    zs[r] = zb;
    z_rm[(size_t)row * GF + f] = zb;
  }
  unsigned int p[8];
#pragma unroll
  for (int i = 0; i < 8; ++i)
    p[i] = (unsigned int)zs[2 * i] | ((unsigned int)zs[2 * i + 1] << 16);
  char* dst = (char*)z2 + (size_t)((rowB >> 5) + (w >> 1)) * 4096 + f * 64 + (w & 1) * 32;
  u32x4 lo = {p[0], p[1], p[2], p[3]};
  u32x4 hi = {p[4], p[5], p[6], p[7]};
  *(u32x4*)dst = lo;
  *(u32x4*)(dst + 16) = hi;
}

// ---------------------------------------------------------------------------
// K3 v3: R4 structure + SOFTWARE PIPELINE. Chunk c+1's 4 B-fragment loads are
// issued BEFORE chunk c's decode+MFMA (per-step non-load work ~286 cyc > ~220
// cyc L2 latency -> fully hidden). Bits prefetched one iter ahead. Tail
// prefetches over-read into mapped neighbors (values never consumed).
// ---------------------------------------------------------------------------
__global__ __launch_bounds__(256) void k_spmm(const unsigned int* __restrict__ packed,
                                              const unsigned short* __restrict__ z2,
                                              const unsigned short* __restrict__ z_rm,
                                              const float* __restrict__ dinv,
                                              const float* __restrict__ bias,
                                              float* __restrict__ out) {
  __shared__ float red[4][64][64];  // 64 KB split-K partials
  const int i0 = blockIdx.x * 64;
  const int tid = threadIdx.x;
  const int wave = tid >> 6, lane = tid & 63;
  const int lrow = lane & 15, kb = lane >> 4;

  f32x4 acc[4][4];
#pragma unroll
  for (int mr = 0; mr < 4; ++mr)
#pragma unroll
    for (int nr = 0; nr < 4; ++nr) acc[mr][nr] = (f32x4){0.f, 0.f, 0.f, 0.f};

  const unsigned int* pr0 = packed + (size_t)(i0 + 0 * 16 + lrow) * NW + wave * 128;
  const unsigned int* pr1 = packed + (size_t)(i0 + 1 * 16 + lrow) * NW + wave * 128;
  const unsigned int* pr2 = packed + (size_t)(i0 + 2 * 16 + lrow) * NW + wave * 128;
  const unsigned int* pr3 = packed + (size_t)(i0 + 3 * 16 + lrow) * NW + wave * 128;
  const char* zbase = (const char*)z2 + (size_t)(wave * 128) * 4096 + lrow * 64 + kb * 16;
  const int sh = kb * 8;

  // pipeline prologue: first chunk's B-fragments + first bits
  bf16x8 cur0 = *(const bf16x8*)(zbase + 0 * 1024);
  bf16x8 cur1 = *(const bf16x8*)(zbase + 1 * 1024);
  bf16x8 cur2 = *(const bf16x8*)(zbase + 2 * 1024);
  bf16x8 cur3 = *(const bf16x8*)(zbase + 3 * 1024);
  u32x4 bits0 = *(const u32x4*)pr0;
  u32x4 bits1 = *(const u32x4*)pr1;
  u32x4 bits2 = *(const u32x4*)pr2;
  u32x4 bits3 = *(const u32x4*)pr3;

  for (int it = 0; it < 32; ++it) {
    // prefetch next iteration's bits (tail read lands in 64 B ws slack)
    u32x4 nb0 = *(const u32x4*)(pr0 + 4);
    u32x4 nb1 = *(const u32x4*)(pr1 + 4);
    u32x4 nb2 = *(const u32x4*)(pr2 + 4);
    u32x4 nb3 = *(const u32x4*)(pr3 + 4);
#pragma unroll
    for (int s = 0; s < 4; ++s) {    // 4 MFMA k-steps of 32
      // prefetch chunk (it,s)+1 BEFORE consuming chunk (it,s)
      const char* zn = zbase + (s + 1) * 4096;
      bf16x8 n0 = *(const bf16x8*)(zn + 0 * 1024);
      bf16x8 n1 = *(const bf16x8*)(zn + 1 * 1024);
      bf16x8 n2 = *(const bf16x8*)(zn + 2 * 1024);
      bf16x8 n3 = *(const bf16x8*)(zn + 3 * 1024);

      bf16x8 a0 = decode8((bits0[s] >> sh) & 0xffu);
      acc[0][0] = __builtin_amdgcn_mfma_f32_16x16x32_bf16(a0, cur0, acc[0][0], 0, 0, 0);
      acc[0][1] = __builtin_amdgcn_mfma_f32_16x16x32_bf16(a0, cur1, acc[0][1], 0, 0, 0);
      acc[0][2] = __builtin_amdgcn_mfma_f32_16x16x32_bf16(a0, cur2, acc[0][2], 0, 0, 0);
      acc[0][3] = __builtin_amdgcn_mfma_f32_16x16x32_bf16(a0, cur3, acc[0][3], 0, 0, 0);
      bf16x8 a1 = decode8((bits1[s] >> sh) & 0xffu);
      acc[1][0] = __builtin_amdgcn_mfma_f32_16x16x32_bf16(a1, cur0, acc[1][0], 0, 0, 0);
      acc[1][1] = __builtin_amdgcn_mfma_f32_16x16x32_bf16(a1, cur1, acc[1][1], 0, 0, 0);
      acc[1][2] = __builtin_amdgcn_mfma_f32_16x16x32_bf16(a1, cur2, acc[1][2], 0, 0, 0);
      acc[1][3] = __builtin_amdgcn_mfma_f32_16x16x32_bf16(a1, cur3, acc[1][3], 0, 0, 0);
      bf16x8 a2 = decode8((bits2[s] >> sh) & 0xffu);
      acc[2][0] = __builtin_amdgcn_mfma_f32_16x16x32_bf16(a2, cur0, acc[2][0], 0, 0, 0);
      acc[2][1] = __builtin_amdgcn_mfma_f32_16x16x32_bf16(a2, cur1, acc[2][1], 0, 0, 0);
      acc[2][2] = __builtin_amdgcn_mfma_f32_16x16x32_bf16(a2, cur2, acc[2][2], 0, 0, 0);
      acc[2][3] = __builtin_amdgcn_mfma_f32_16x16x32_bf16(a2, cur3, acc[2][3], 0, 0, 0);
      bf16x8 a3 = decode8((bits3[s] >> sh) & 0xffu);
      acc[3][0] = __builtin_amdgcn_mfma_f32_16x16x32_bf16(a3, cur0, acc[3][0], 0, 0, 0);
      acc[3][1] = __builtin_amdgcn_mfma_f32_16x16x32_bf16(a3, cur1, acc[3][1], 0, 0, 0);
      acc[3][2] = __builtin_amdgcn_mfma_f32_16x16x32_bf16(a3, cur2, acc[3][2], 0, 0, 0);
      acc[3][3] = __builtin_amdgcn_mfma_f32_16x16x32_bf16(a3, cur3, acc[3][3], 0, 0, 0);

      cur0 = n0; cur1 = n1; cur2 = n2; cur3 = n3;
    }
    bits0 = nb0; bits1 = nb1; bits2 = nb2; bits3 = nb3;
    pr0 += 4; pr1 += 4; pr2 += 4; pr3 += 4;
    zbase += 16384;  // 4 chunks
  }

#pragma unroll
  for (int mr = 0; mr < 4; ++mr)
#pragma unroll
    for (int nr = 0; nr < 4; ++nr)
#pragma unroll
      for (int r = 0; r < 4; ++r)
        red[wave][mr * 16 + kb * 4 + r][nr * 16 + lrow] = acc[mr][nr][r];
  __syncthreads();

  const int c = tid & 63;
  const int r0 = tid >> 6;
  const float bc = bias[c];
#pragma unroll
  for (int rr = 0; rr < 16; ++rr) {
    int r = r0 * 16 + rr;
    int i = i0 + r;
    float s = red[0][r][c] + red[1][r][c] + red[2][r][c] + red[3][r][c];
    float o = dinv[i] * (s + bf2f(z_rm[(size_t)i * GF + c])) + bc;
    out[(size_t)i * GF + c] = fmaxf(o, 0.f);
  }
}

// ---------------------------------------------------------------------------
extern "C" void kernel_launch(void* const* d_in, const int* in_sizes, int n_in,
                              void* d_out, int out_size, void* d_ws, size_t ws_size,
                              hipStream_t stream) {
  const float* x = (const float*)d_in[0];
  const float* adj = (const float*)d_in[1];
  const float* W = (const float*)d_in[2];
  const float* bias = (const float*)d_in[3];
  float* out = (float*)d_out;

  char* ws = (char*)d_ws;
  float* deg = (float*)ws;                                        // 64 KB
  float* dinv = (float*)(ws + 65536);                             // 64 KB
  unsigned short* z_rm = (unsigned short*)(ws + 131072);          // 2 MB
  unsigned short* z2 = (unsigned short*)(ws + 131072 + 2097152);  // 2 MB chunk-tiled
  unsigned int* packed = (unsigned int*)(ws + 131072 + 4194304);  // 32 MB + 64 B slack
  if (ws_size < 37879872u) return;

  hipMemsetAsync(deg, 0, GN * sizeof(float), stream);
  k_pack<<<dim3(512), dim3(256), 0, stream>>>(adj, deg, packed);
  k_z<<<dim3(GN / 64), dim3(256), 0, stream>>>(x, W, deg, dinv, z_rm, z2);
  k_spmm<<<dim3(GN / 64), dim3(256), 0, stream>>>(packed, z2, z_rm, dinv, bias, out);
}